// Round 4
// baseline (989.037 us; speedup 1.0000x reference)
//
#include <hip/hip_runtime.h>
#include <hip/hip_bf16.h>
#include <stdint.h>

#define N_NODES 100000
#define D_IN 512
#define D_H 128
#define N_EDGES 1600000
#define X_ELEMS (N_NODES * D_IN)   // 51,200,000

// ---------------- threefry2x32 (JAX-compatible, 20 rounds) ----------------
__host__ __device__ inline void threefry2x32(uint32_t k0, uint32_t k1,
                                             uint32_t x0, uint32_t x1,
                                             uint32_t& o0, uint32_t& o1) {
  uint32_t k2 = k0 ^ k1 ^ 0x1BD11BDAu;
  x0 += k0; x1 += k1;
#define TFR(r) x0 += x1; x1 = (x1 << (r)) | (x1 >> (32 - (r))); x1 ^= x0;
  TFR(13) TFR(15) TFR(26) TFR(6)
  x0 += k1; x1 += k2 + 1u;
  TFR(17) TFR(29) TFR(16) TFR(24)
  x0 += k2; x1 += k0 + 2u;
  TFR(13) TFR(15) TFR(26) TFR(6)
  x0 += k0; x1 += k1 + 3u;
  TFR(17) TFR(29) TFR(16) TFR(24)
  x0 += k1; x1 += k2 + 4u;
  TFR(13) TFR(15) TFR(26) TFR(6)
  x0 += k2; x1 += k0 + 5u;
#undef TFR
  o0 = x0; o1 = x1;
}

// partitionable random_bits for index i (< 2^32): xor of the two output lanes
__device__ inline uint32_t tf_bits(uint32_t k0, uint32_t k1, uint32_t i) {
  uint32_t w0, w1;
  threefry2x32(k0, k1, 0u, i, w0, w1);
  return w0 ^ w1;
}

__device__ inline float bits_to_unit(uint32_t b) {
  return __uint_as_float((b >> 9) | 0x3f800000u) - 1.0f;
}

__device__ inline unsigned short f2bf(float f) {  // RNE, finite inputs only
  uint32_t b = __float_as_uint(f);
  return (unsigned short)((b + 0x7FFFu + ((b >> 16) & 1u)) >> 16);
}

// Giles (2012) single-precision erfinv: ~1e-6 rel err, branch-free select.
__device__ inline float erfinv_fast(float x) {
  float w = -__logf((1.0f - x) * (1.0f + x));
  // central branch (w < 5)
  float wc = w - 2.5f;
  float p = 2.81022636e-08f;
  p = fmaf(p, wc, 3.43273939e-07f);
  p = fmaf(p, wc, -3.5233877e-06f);
  p = fmaf(p, wc, -4.39150654e-06f);
  p = fmaf(p, wc, 0.00021858087f);
  p = fmaf(p, wc, -0.00125372503f);
  p = fmaf(p, wc, -0.00417768164f);
  p = fmaf(p, wc, 0.246640727f);
  p = fmaf(p, wc, 1.50140941f);
  // tail branch (w >= 5)
  float wt = __builtin_sqrtf(w) - 3.0f;
  float q = -0.000200214257f;
  q = fmaf(q, wt, 0.000100950558f);
  q = fmaf(q, wt, 0.00134934322f);
  q = fmaf(q, wt, -0.00367342844f);
  q = fmaf(q, wt, 0.00573950773f);
  q = fmaf(q, wt, -0.0076224613f);
  q = fmaf(q, wt, 0.00943887047f);
  q = fmaf(q, wt, 1.00167406f);
  q = fmaf(q, wt, 2.83297682f);
  return ((w < 5.0f) ? p : q) * x;
}

// ---------------- 1. noise + double dropout -> x (bf16) ----------------
__global__ __launch_bounds__(256) void gen_x_kernel(
    const float* __restrict__ data, unsigned short* __restrict__ x,
    uint32_t kn0, uint32_t kn1, uint32_t kd10, uint32_t kd11,
    uint32_t kd20, uint32_t kd21) {
  uint32_t t = blockIdx.x * 256u + threadIdx.x;
  uint32_t base = t * 8u;
  if (base >= (uint32_t)X_ELEMS) return;
  float4 d0 = *(const float4*)(data + base);
  float4 d1 = *(const float4*)(data + base + 4);
  float dv[8] = {d0.x, d0.y, d0.z, d0.w, d1.x, d1.y, d1.z, d1.w};
  unsigned short s[8];
  const float lo = -0.99999994f;  // nextafter(-1,0); (1-lo) rounds to exactly 2.0f
  for (int j = 0; j < 8; ++j) {
    uint32_t i = base + (uint32_t)j;
    uint32_t nb = tf_bits(kn0, kn1, i);    // gaussian noise bits
    uint32_t ab = tf_bits(kd10, kd11, i);  // dropout mask 1
    uint32_t bb = tf_bits(kd20, kd21, i);  // dropout mask 2
    float f = bits_to_unit(nb);
    float u = f * 2.0f + lo;               // >= lo always (f >= 0), clamp not needed
    float z = 1.41421356237309515f * erfinv_fast(u);
    // bernoulli(0.5): uniform < 0.5  <=>  top bit of bits clear
    float s01 = (((ab | bb) & 0x80000000u) == 0u) ? 4.0f : 0.0f;  // 1/(0.5*0.5)
    s[j] = f2bf((dv[j] + 0.01f * z) * s01);
  }
  *(ushort4*)(x + base) = make_ushort4(s[0], s[1], s[2], s[3]);
  *(ushort4*)(x + base + 4) = make_ushort4(s[4], s[5], s[6], s[7]);
}

// ---------------- 2. W (f32 [512][128]) -> Wt (bf16 [128][512]) ----------------
__global__ __launch_bounds__(256) void wt_kernel(const float* __restrict__ W,
                                                 unsigned short* __restrict__ Wt) {
  int id = blockIdx.x * 256 + threadIdx.x;  // 65536
  int k = id >> 7, n = id & 127;
  Wt[n * 512 + k] = f2bf(W[id]);
}

// ---------------- 3. h = x @ W  (bf16 MFMA, f32 acc) ----------------
typedef __attribute__((ext_vector_type(8))) short bf16x8;
typedef __attribute__((ext_vector_type(4))) float f32x4;
#define BM 64
#define BK 64
#define LDT 72  // padded LDS leading dim (elements)

__global__ __launch_bounds__(256) void gemm_kernel(
    const unsigned short* __restrict__ x, const unsigned short* __restrict__ Wt,
    float* __restrict__ h) {
  __shared__ __align__(16) unsigned short a_lds[BM * LDT];
  __shared__ __align__(16) unsigned short b_lds[128 * LDT];
  const int tid = threadIdx.x;
  const int r0 = blockIdx.x * BM;
  const int wave = tid >> 6, lane = tid & 63;
  const int lane15 = lane & 15, quad = lane >> 4;
  const int waveM = (wave & 1) * 32, waveN = (wave >> 1) * 64;
  f32x4 acc[2][4] = {};
  for (int kc = 0; kc < D_IN; kc += BK) {
    __syncthreads();
    {  // stage A tile: 64 rows x 64 k
      int row = tid >> 2, q = tid & 3;
      int gr = r0 + row;
      uint4 v0 = make_uint4(0, 0, 0, 0), v1 = v0;
      if (gr < N_NODES) {
        const unsigned short* src = x + (size_t)gr * D_IN + kc + q * 16;
        v0 = *(const uint4*)(src);
        v1 = *(const uint4*)(src + 8);
      }
      *(uint4*)(a_lds + row * LDT + q * 16) = v0;
      *(uint4*)(a_lds + row * LDT + q * 16 + 8) = v1;
    }
    {  // stage B tile: 128 cols x 64 k (Wt is [n][k] row-major)
      int n = tid >> 1, half = tid & 1;
      const uint4* src = (const uint4*)(Wt + n * 512 + kc + half * 32);
      uint4* dst = (uint4*)(b_lds + n * LDT + half * 32);
      dst[0] = src[0]; dst[1] = src[1]; dst[2] = src[2]; dst[3] = src[3];
    }
    __syncthreads();
    for (int ks = 0; ks < BK; ks += 32) {
      bf16x8 afrag[2], bfrag[4];
      for (int m = 0; m < 2; ++m)
        afrag[m] = *(const bf16x8*)(a_lds + (waveM + m * 16 + lane15) * LDT + ks + quad * 8);
      for (int n = 0; n < 4; ++n)
        bfrag[n] = *(const bf16x8*)(b_lds + (waveN + n * 16 + lane15) * LDT + ks + quad * 8);
      for (int m = 0; m < 2; ++m)
        for (int n = 0; n < 4; ++n)
          acc[m][n] = __builtin_amdgcn_mfma_f32_16x16x32_bf16(afrag[m], bfrag[n], acc[m][n], 0, 0, 0);
    }
  }
  // C/D layout: col = lane&15, row = quad*4 + reg  [verified m89]
  for (int m = 0; m < 2; ++m) {
    int growb = r0 + waveM + m * 16 + quad * 4;
    for (int r = 0; r < 4; ++r) {
      int grow = growb + r;
      if (grow < N_NODES)
        for (int n = 0; n < 4; ++n)
          h[(size_t)grow * D_H + waveN + n * 16 + lane15] = acc[m][n][r];
    }
  }
}

// ---------------- 4. zero counts + stats ----------------
__global__ __launch_bounds__(256) void zero_kernel(int* __restrict__ counts,
                                                   float* __restrict__ stats) {
  int idx = blockIdx.x * 256 + threadIdx.x;
  if (idx < N_NODES) counts[idx] = 0;
  if (idx < 256) stats[idx] = 0.0f;
}

// ---------------- 4b. index layout detect + unpack (int32 vs int64) ----------------
__global__ void detect_kernel(const int* __restrict__ adj32, int* __restrict__ flag) {
  int i = threadIdx.x;  // 64 lanes
  bool hi_zero = (adj32[2 * i + 1] == 0);
  unsigned long long b = __ballot(hi_zero);
  if (i == 0) *flag = (b == ~0ull) ? 1 : 0;  // all-hi-words-zero => int64 layout
}

__global__ __launch_bounds__(256) void unpack_kernel(const int* __restrict__ adj32,
                                                     const int* __restrict__ flag,
                                                     int* __restrict__ idxc) {
  int e = blockIdx.x * 256 + threadIdx.x;  // 2*N_EDGES
  if (e >= 2 * N_EDGES) return;
  idxc[e] = (*flag) ? adj32[2 * e] : adj32[e];
}

// ---------------- 5. edge dropout ----------------
__global__ __launch_bounds__(256) void edge_kernel(const float* __restrict__ vals,
                                                   float* __restrict__ vmasked,
                                                   uint32_t ke0, uint32_t ke1) {
  uint32_t t = blockIdx.x * 256u + threadIdx.x;
  uint32_t base = t * 4u;
  if (base >= (uint32_t)N_EDGES) return;
  const float pe = 0.60000002384185791f;  // (float)(1.0 - 0.4)
  for (int j = 0; j < 4; ++j) {
    uint32_t e = base + (uint32_t)j;
    uint32_t eb = tf_bits(ke0, ke1, e);
    vmasked[e] = (bits_to_unit(eb) < pe) ? vals[e] / pe : 0.0f;
  }
}

// ---------------- 6a. histogram of kept edges per destination row ----------------
__global__ __launch_bounds__(256) void hist_kernel(const int* __restrict__ idxc,
                                                   const float* __restrict__ vmasked,
                                                   int* __restrict__ counts) {
  int e = blockIdx.x * 256 + threadIdx.x;
  if (e >= N_EDGES) return;
  if (vmasked[e] != 0.0f) atomicAdd(&counts[idxc[e]], 1);
}

// ---------------- 6b. prefix scan (3 kernels) ----------------
#define SCAN_B 512
#define SCAN_NBLK ((N_NODES + SCAN_B - 1) / SCAN_B)  // 196

__global__ __launch_bounds__(256) void scan1_kernel(const int* __restrict__ counts,
                                                    int* __restrict__ rowstart,
                                                    int* __restrict__ bsums) {
  __shared__ int bufA[SCAN_B], bufB[SCAN_B];
  int t = threadIdx.x, b = blockIdx.x;
  int g0 = b * SCAN_B + t, g1 = g0 + 256;
  int v0 = (g0 < N_NODES) ? counts[g0] : 0;
  int v1 = (g1 < N_NODES) ? counts[g1] : 0;
  bufA[t] = v0; bufA[t + 256] = v1;
  __syncthreads();
  int* src = bufA; int* dst = bufB;
  for (int off = 1; off < SCAN_B; off <<= 1) {
    for (int k = t; k < SCAN_B; k += 256)
      dst[k] = src[k] + ((k >= off) ? src[k - off] : 0);
    __syncthreads();
    int* tmp = src; src = dst; dst = tmp;
  }
  if (g0 < N_NODES) rowstart[g0] = src[t] - v0;
  if (g1 < N_NODES) rowstart[g1] = src[t + 256] - v1;
  if (t == 0) bsums[b] = src[SCAN_B - 1];
}

__global__ __launch_bounds__(256) void scan2_kernel(const int* __restrict__ bsums,
                                                    int* __restrict__ bscan) {
  __shared__ int bufA[256], bufB[256];
  int t = threadIdx.x;
  int v = (t < SCAN_NBLK) ? bsums[t] : 0;
  bufA[t] = v;
  __syncthreads();
  int* src = bufA; int* dst = bufB;
  for (int off = 1; off < 256; off <<= 1) {
    dst[t] = src[t] + ((t >= off) ? src[t - off] : 0);
    __syncthreads();
    int* tmp = src; src = dst; dst = tmp;
  }
  if (t < SCAN_NBLK) bscan[t] = src[t] - v;
}

__global__ __launch_bounds__(256) void scan3_kernel(int* __restrict__ rowstart,
                                                    const int* __restrict__ bscan,
                                                    int* __restrict__ cursor) {
  int i = blockIdx.x * 256 + threadIdx.x;
  if (i >= N_NODES) return;
  int v = rowstart[i] + bscan[i / SCAN_B];
  rowstart[i] = v;
  cursor[i] = v;
}

// ---------------- 6c. scatter kept edges into CSR order ----------------
__global__ __launch_bounds__(256) void scatter_kernel(const int* __restrict__ idxc,
                                                      const float* __restrict__ vmasked,
                                                      int* __restrict__ cursor,
                                                      int* __restrict__ scol,
                                                      float* __restrict__ sval) {
  int e = blockIdx.x * 256 + threadIdx.x;
  if (e >= N_EDGES) return;
  float v = vmasked[e];
  if (v == 0.0f) return;
  int pos = atomicAdd(&cursor[idxc[e]], 1);
  scol[pos] = idxc[N_EDGES + e];
  sval[pos] = v;
}

// ---------------- 7. CSR SpMM: one wave per row, write-once ----------------
__global__ __launch_bounds__(256) void spmm_csr_kernel(
    const int* __restrict__ scol, const float* __restrict__ sval,
    const int* __restrict__ rowstart, const int* __restrict__ counts,
    const float* __restrict__ h, float* __restrict__ agg) {
  int r = blockIdx.x * 4 + (threadIdx.x >> 6);
  if (r >= N_NODES) return;
  int lane = threadIdx.x & 63;
  int start = rowstart[r], len = counts[r];
  const float* hp = h + 2 * lane;
  float ax = 0.f, ay = 0.f, bx = 0.f, by = 0.f;
  int j = 0;
  for (; j + 1 < len; j += 2) {
    int c0 = scol[start + j], c1 = scol[start + j + 1];
    float v0 = sval[start + j], v1 = sval[start + j + 1];
    float2 h0 = *(const float2*)(hp + (size_t)c0 * D_H);
    float2 h1 = *(const float2*)(hp + (size_t)c1 * D_H);
    ax = fmaf(v0, h0.x, ax); ay = fmaf(v0, h0.y, ay);
    bx = fmaf(v1, h1.x, bx); by = fmaf(v1, h1.y, by);
  }
  if (j < len) {
    int c0 = scol[start + j];
    float v0 = sval[start + j];
    float2 h0 = *(const float2*)(hp + (size_t)c0 * D_H);
    ax = fmaf(v0, h0.x, ax); ay = fmaf(v0, h0.y, ay);
  }
  *(float2*)(agg + (size_t)r * D_H + 2 * lane) = make_float2(ax + bx, ay + by);
}

// ---------------- 8. BN stats (ELU fused) ----------------
__global__ __launch_bounds__(256) void stats_kernel(const float* __restrict__ agg,
                                                    float* __restrict__ stats,
                                                    int rows_per_block) {
  __shared__ float lsum[256], lsq[256];
  int f = threadIdx.x & 127;
  int ro = threadIdx.x >> 7;
  int rstart = blockIdx.x * rows_per_block;
  int rend = min(rstart + rows_per_block, N_NODES);
  float s = 0.f, q = 0.f;
  for (int r = rstart + ro; r < rend; r += 2) {
    float a = agg[(size_t)r * D_H + f];
    float e = a > 0.f ? a : expm1f(a);
    s += e; q += e * e;
  }
  lsum[threadIdx.x] = s; lsq[threadIdx.x] = q;
  __syncthreads();
  if (threadIdx.x < 128) {
    atomicAdd(&stats[f], lsum[threadIdx.x] + lsum[threadIdx.x + 128]);
    atomicAdd(&stats[128 + f], lsq[threadIdx.x] + lsq[threadIdx.x + 128]);
  }
}

// ---------------- 9. BN apply ----------------
__global__ __launch_bounds__(256) void bn_kernel(const float* __restrict__ agg,
                                                 const float* __restrict__ stats,
                                                 const float* __restrict__ gamma,
                                                 const float* __restrict__ beta,
                                                 float* __restrict__ out) {
  int idx4 = blockIdx.x * 256 + threadIdx.x;  // 3.2M threads
  size_t base = (size_t)idx4 * 4;
  if (base >= (size_t)N_NODES * D_H) return;
  int f0 = (int)(base & 127);
  float4 a = *(const float4*)(agg + base);
  float av[4] = {a.x, a.y, a.z, a.w};
  const float inv_n = 1.0f / (float)N_NODES;
  float o[4];
  for (int j = 0; j < 4; ++j) {
    int f = f0 + j;
    float mean = stats[f] * inv_n;
    float var = stats[128 + f] * inv_n - mean * mean;
    float e = av[j] > 0.f ? av[j] : expm1f(av[j]);
    o[j] = gamma[f] * (e - mean) * rsqrtf(var + 1e-5f) + beta[f];
  }
  *(float4*)(out + base) = make_float4(o[0], o[1], o[2], o[3]);
}

// ---------------- launcher ----------------
extern "C" void kernel_launch(void* const* d_in, const int* in_sizes, int n_in,
                              void* d_out, int out_size, void* d_ws, size_t ws_size,
                              hipStream_t stream) {
  const float* data = (const float*)d_in[0];
  const int* adj = (const int*)d_in[1];
  const float* vals = (const float*)d_in[2];
  const float* W = (const float*)d_in[3];
  const float* gamma = (const float*)d_in[4];
  const float* beta = (const float*)d_in[5];
  float* out = (float*)d_out;

  // workspace layout (~153.8 MB). x [0,102.4M) is dead after gemm; everything
  // in [0,102.4M) below is only written AFTER gemm (stream order enforces).
  char* ws = (char*)d_ws;
  unsigned short* x = (unsigned short*)ws;            // [0, 102.4M) bf16
  float* agg = (float*)ws;                            // [0, 51.2M) alias
  int* idxc = (int*)(ws + 51200000);                  // 12.8 MB
  float* vmasked = (float*)(ws + 64000000);           // 6.4 MB
  int* scol = (int*)(ws + 70400000);                  // 6.4 MB
  float* sval = (float*)(ws + 76800000);              // 6.4 MB
  int* counts = (int*)(ws + 83200000);                // 400 KB
  int* rowstart = (int*)(ws + 83600000);              // 400 KB
  int* cursor = (int*)(ws + 84000000);                // 400 KB
  int* bsums = (int*)(ws + 84400000);                 // 784 B
  int* bscan = (int*)(ws + 84401024);                 // 784 B
  float* h = (float*)(ws + 102400000);                // 51.2 MB
  unsigned short* Wt = (unsigned short*)(ws + 153600000);  // 128 KB
  float* stats = (float*)(ws + 153731072);            // 1 KB
  int* flag = (int*)(ws + 153732096);                 // 4 B

  // host-side: split(key(42), 4) foldlike -> key_i = both words of tf(key,(0,i))
  uint32_t kk[4][2];
  for (uint32_t i = 0; i < 4; ++i) threefry2x32(0u, 42u, 0u, i, kk[i][0], kk[i][1]);
  uint32_t kn0 = kk[0][0], kn1 = kk[0][1];
  uint32_t kd10 = kk[1][0], kd11 = kk[1][1];
  uint32_t kd20 = kk[2][0], kd21 = kk[2][1];
  uint32_t ke0 = kk[3][0], ke1 = kk[3][1];

  gen_x_kernel<<<25000, 256, 0, stream>>>(data, x, kn0, kn1, kd10, kd11, kd20, kd21);
  wt_kernel<<<256, 256, 0, stream>>>(W, Wt);
  gemm_kernel<<<(N_NODES + BM - 1) / BM, 256, 0, stream>>>(x, Wt, h);
  // ---- everything below may reuse x's memory (x dead) ----
  zero_kernel<<<391, 256, 0, stream>>>(counts, stats);
  detect_kernel<<<1, 64, 0, stream>>>(adj, flag);
  unpack_kernel<<<12500, 256, 0, stream>>>(adj, flag, idxc);
  edge_kernel<<<1563, 256, 0, stream>>>(vals, vmasked, ke0, ke1);
  hist_kernel<<<6250, 256, 0, stream>>>(idxc, vmasked, counts);
  scan1_kernel<<<SCAN_NBLK, 256, 0, stream>>>(counts, rowstart, bsums);
  scan2_kernel<<<1, 256, 0, stream>>>(bsums, bscan);
  scan3_kernel<<<391, 256, 0, stream>>>(rowstart, bscan, cursor);
  scatter_kernel<<<6250, 256, 0, stream>>>(idxc, vmasked, cursor, scol, sval);
  spmm_csr_kernel<<<25000, 256, 0, stream>>>(scol, sval, rowstart, counts, h, agg);
  stats_kernel<<<400, 256, 0, stream>>>(agg, stats, 250);
  bn_kernel<<<12500, 256, 0, stream>>>(agg, stats, gamma, beta, out);
}

// Round 5
// 824.643 us; speedup vs baseline: 1.1994x; 1.1994x over previous
//
#include <hip/hip_runtime.h>
#include <hip/hip_bf16.h>
#include <stdint.h>

#define N_NODES 100000
#define D_IN 512
#define D_H 128
#define N_EDGES 1600000
#define X_ELEMS (N_NODES * D_IN)   // 51,200,000

// ---------------- threefry2x32 (JAX-compatible, 20 rounds) ----------------
__host__ __device__ __forceinline__ void threefry2x32(uint32_t k0, uint32_t k1,
                                                      uint32_t x0, uint32_t x1,
                                                      uint32_t& o0, uint32_t& o1) {
  uint32_t k2 = k0 ^ k1 ^ 0x1BD11BDAu;
  x0 += k0; x1 += k1;
#if defined(__HIP_DEVICE_COMPILE__)
#define ROTL(v, r) __builtin_rotateleft32((v), (r))
#else
#define ROTL(v, r) (((v) << (r)) | ((v) >> (32 - (r))))
#endif
#define TFR(r) x0 += x1; x1 = ROTL(x1, r); x1 ^= x0;
  TFR(13) TFR(15) TFR(26) TFR(6)
  x0 += k1; x1 += k2 + 1u;
  TFR(17) TFR(29) TFR(16) TFR(24)
  x0 += k2; x1 += k0 + 2u;
  TFR(13) TFR(15) TFR(26) TFR(6)
  x0 += k0; x1 += k1 + 3u;
  TFR(17) TFR(29) TFR(16) TFR(24)
  x0 += k1; x1 += k2 + 4u;
  TFR(13) TFR(15) TFR(26) TFR(6)
  x0 += k2; x1 += k0 + 5u;
#undef TFR
#undef ROTL
  o0 = x0; o1 = x1;
}

// partitionable random_bits for index i (< 2^32): xor of the two output lanes
__device__ __forceinline__ uint32_t tf_bits(uint32_t k0, uint32_t k1, uint32_t i) {
  uint32_t w0, w1;
  threefry2x32(k0, k1, 0u, i, w0, w1);
  return w0 ^ w1;
}

__device__ __forceinline__ float bits_to_unit(uint32_t b) {
  return __uint_as_float((b >> 9) | 0x3f800000u) - 1.0f;
}

__device__ __forceinline__ unsigned short f2bf(float f) {  // RNE, finite only
  uint32_t b = __float_as_uint(f);
  return (unsigned short)((b + 0x7FFFu + ((b >> 16) & 1u)) >> 16);
}

// Giles (2012) single-precision erfinv: ~1e-6 rel err, branch-free select.
__device__ __forceinline__ float erfinv_fast(float x) {
  float w = -__logf(fmaf(-x, x, 1.0f));
  float wc = w - 2.5f;
  float p = 2.81022636e-08f;
  p = fmaf(p, wc, 3.43273939e-07f);
  p = fmaf(p, wc, -3.5233877e-06f);
  p = fmaf(p, wc, -4.39150654e-06f);
  p = fmaf(p, wc, 0.00021858087f);
  p = fmaf(p, wc, -0.00125372503f);
  p = fmaf(p, wc, -0.00417768164f);
  p = fmaf(p, wc, 0.246640727f);
  p = fmaf(p, wc, 1.50140941f);
  float wt = __builtin_sqrtf(w) - 3.0f;
  float q = -0.000200214257f;
  q = fmaf(q, wt, 0.000100950558f);
  q = fmaf(q, wt, 0.00134934322f);
  q = fmaf(q, wt, -0.00367342844f);
  q = fmaf(q, wt, 0.00573950773f);
  q = fmaf(q, wt, -0.0076224613f);
  q = fmaf(q, wt, 0.00943887047f);
  q = fmaf(q, wt, 1.00167406f);
  q = fmaf(q, wt, 2.83297682f);
  return ((w < 5.0f) ? p : q) * x;
}

// one element of noise+dropout+dropout, straight-line
__device__ __forceinline__ unsigned short gen1(
    float d, uint32_t i, uint32_t kn0, uint32_t kn1, uint32_t kd10,
    uint32_t kd11, uint32_t kd20, uint32_t kd21) {
  uint32_t nb = tf_bits(kn0, kn1, i);
  uint32_t ab = tf_bits(kd10, kd11, i);
  uint32_t bb = tf_bits(kd20, kd21, i);
  float f = bits_to_unit(nb);
  float u = fmaf(f, 2.0f, -0.99999994f);  // >= -0.99999994 always
  float z = erfinv_fast(u);
  // noise scale 0.01 * sqrt(2) folded (we approximate erfinv anyway)
  float val = fmaf(0.0141421356237f, z, d);
  float s01 = (((ab | bb) & 0x80000000u) == 0u) ? 4.0f : 0.0f;
  return f2bf(val * s01);
}

// ---------------- fused: gen_x (4/5 blocks) + edge-hist (1/5) + wt ----------------
#define GEN_BLKS 25000
#define EDGE_BLKS 6250
#define MAIN_BLKS 31250           // GEN + EDGE interleaved 4:1
#define WT_BLKS 256
#define PE 0.60000002384185791f   // (float)(1.0 - 0.4)

__global__ __launch_bounds__(256) void fused_kernel(
    const float* __restrict__ data, unsigned short* __restrict__ x,
    const int* __restrict__ adj32, const int* __restrict__ flag,
    int* __restrict__ counts, const float* __restrict__ W,
    unsigned short* __restrict__ Wt,
    uint32_t kn0, uint32_t kn1, uint32_t kd10, uint32_t kd11,
    uint32_t kd20, uint32_t kd21, uint32_t ke0, uint32_t ke1) {
  int b = blockIdx.x;
  if (b < MAIN_BLKS) {
    if ((b % 5) == 4) {
      // ---- edge-hist block ----
      uint32_t e = (uint32_t)(b / 5) * 256u + threadIdx.x;  // < 1.6M exactly
      int fl = *flag;
      int r = fl ? adj32[2 * e] : adj32[e];
      uint32_t eb = tf_bits(ke0, ke1, e);
      if (bits_to_unit(eb) < PE) atomicAdd(&counts[r], 1);
    } else {
      // ---- gen_x block ----
      uint32_t gblk = (uint32_t)(b / 5) * 4u + (uint32_t)(b % 5);
      uint32_t t = gblk * 256u + threadIdx.x;
      uint32_t base = t * 8u;  // 25000*256*8 == X_ELEMS exactly
      float4 d0 = *(const float4*)(data + base);
      float4 d1 = *(const float4*)(data + base + 4);
      unsigned short s0 = gen1(d0.x, base + 0, kn0, kn1, kd10, kd11, kd20, kd21);
      unsigned short s1 = gen1(d0.y, base + 1, kn0, kn1, kd10, kd11, kd20, kd21);
      unsigned short s2 = gen1(d0.z, base + 2, kn0, kn1, kd10, kd11, kd20, kd21);
      unsigned short s3 = gen1(d0.w, base + 3, kn0, kn1, kd10, kd11, kd20, kd21);
      unsigned short s4 = gen1(d1.x, base + 4, kn0, kn1, kd10, kd11, kd20, kd21);
      unsigned short s5 = gen1(d1.y, base + 5, kn0, kn1, kd10, kd11, kd20, kd21);
      unsigned short s6 = gen1(d1.z, base + 6, kn0, kn1, kd10, kd11, kd20, kd21);
      unsigned short s7 = gen1(d1.w, base + 7, kn0, kn1, kd10, kd11, kd20, kd21);
      *(ushort4*)(x + base) = make_ushort4(s0, s1, s2, s3);
      *(ushort4*)(x + base + 4) = make_ushort4(s4, s5, s6, s7);
    }
  } else {
    // ---- wt block: W (f32 [512][128]) -> Wt (bf16 [128][512]) ----
    int id = (b - MAIN_BLKS) * 256 + threadIdx.x;  // 65536
    int k = id >> 7, n = id & 127;
    Wt[n * 512 + k] = f2bf(W[id]);
  }
}

// ---------------- gemm: h = x @ W (bf16 MFMA, f32 acc) ----------------
typedef __attribute__((ext_vector_type(8))) short bf16x8;
typedef __attribute__((ext_vector_type(4))) float f32x4;
#define BM 64
#define BK 64
#define LDT 72  // padded LDS leading dim (elements)

__global__ __launch_bounds__(256) void gemm_kernel(
    const unsigned short* __restrict__ x, const unsigned short* __restrict__ Wt,
    float* __restrict__ h) {
  __shared__ __align__(16) unsigned short a_lds[BM * LDT];
  __shared__ __align__(16) unsigned short b_lds[128 * LDT];
  const int tid = threadIdx.x;
  const int r0 = blockIdx.x * BM;
  const int wave = tid >> 6, lane = tid & 63;
  const int lane15 = lane & 15, quad = lane >> 4;
  const int waveM = (wave & 1) * 32, waveN = (wave >> 1) * 64;
  f32x4 acc[2][4] = {};
  for (int kc = 0; kc < D_IN; kc += BK) {
    __syncthreads();
    {
      int row = tid >> 2, q = tid & 3;
      int gr = r0 + row;
      uint4 v0 = make_uint4(0, 0, 0, 0), v1 = v0;
      if (gr < N_NODES) {
        const unsigned short* src = x + (size_t)gr * D_IN + kc + q * 16;
        v0 = *(const uint4*)(src);
        v1 = *(const uint4*)(src + 8);
      }
      *(uint4*)(a_lds + row * LDT + q * 16) = v0;
      *(uint4*)(a_lds + row * LDT + q * 16 + 8) = v1;
    }
    {
      int n = tid >> 1, half = tid & 1;
      const uint4* src = (const uint4*)(Wt + n * 512 + kc + half * 32);
      uint4* dst = (uint4*)(b_lds + n * LDT + half * 32);
      dst[0] = src[0]; dst[1] = src[1]; dst[2] = src[2]; dst[3] = src[3];
    }
    __syncthreads();
    for (int ks = 0; ks < BK; ks += 32) {
      bf16x8 afrag[2], bfrag[4];
      for (int m = 0; m < 2; ++m)
        afrag[m] = *(const bf16x8*)(a_lds + (waveM + m * 16 + lane15) * LDT + ks + quad * 8);
      for (int n = 0; n < 4; ++n)
        bfrag[n] = *(const bf16x8*)(b_lds + (waveN + n * 16 + lane15) * LDT + ks + quad * 8);
      for (int m = 0; m < 2; ++m)
        for (int n = 0; n < 4; ++n)
          acc[m][n] = __builtin_amdgcn_mfma_f32_16x16x32_bf16(afrag[m], bfrag[n], acc[m][n], 0, 0, 0);
    }
  }
  for (int m = 0; m < 2; ++m) {
    int growb = r0 + waveM + m * 16 + quad * 4;
    for (int r = 0; r < 4; ++r) {
      int grow = growb + r;
      if (grow < N_NODES)
        for (int n = 0; n < 4; ++n)
          h[(size_t)grow * D_H + waveN + n * 16 + lane15] = acc[m][n][r];
    }
  }
}

// ---------------- zero counts + stats ----------------
__global__ __launch_bounds__(256) void zero_kernel(int* __restrict__ counts,
                                                   float* __restrict__ stats) {
  int idx = blockIdx.x * 256 + threadIdx.x;
  if (idx < N_NODES) counts[idx] = 0;
  if (idx < 256) stats[idx] = 0.0f;
}

// ---------------- index layout detect (int32 vs int64) ----------------
__global__ void detect_kernel(const int* __restrict__ adj32, int* __restrict__ flag) {
  int i = threadIdx.x;  // 64 lanes
  bool hi_zero = (adj32[2 * i + 1] == 0);
  unsigned long long b = __ballot(hi_zero);
  if (i == 0) *flag = (b == ~0ull) ? 1 : 0;
}

// ---------------- prefix scan (3 kernels) ----------------
#define SCAN_B 512
#define SCAN_NBLK ((N_NODES + SCAN_B - 1) / SCAN_B)  // 196

__global__ __launch_bounds__(256) void scan1_kernel(const int* __restrict__ counts,
                                                    int* __restrict__ rowstart,
                                                    int* __restrict__ bsums) {
  __shared__ int bufA[SCAN_B], bufB[SCAN_B];
  int t = threadIdx.x, b = blockIdx.x;
  int g0 = b * SCAN_B + t, g1 = g0 + 256;
  int v0 = (g0 < N_NODES) ? counts[g0] : 0;
  int v1 = (g1 < N_NODES) ? counts[g1] : 0;
  bufA[t] = v0; bufA[t + 256] = v1;
  __syncthreads();
  int* src = bufA; int* dst = bufB;
  for (int off = 1; off < SCAN_B; off <<= 1) {
    for (int k = t; k < SCAN_B; k += 256)
      dst[k] = src[k] + ((k >= off) ? src[k - off] : 0);
    __syncthreads();
    int* tmp = src; src = dst; dst = tmp;
  }
  if (g0 < N_NODES) rowstart[g0] = src[t] - v0;
  if (g1 < N_NODES) rowstart[g1] = src[t + 256] - v1;
  if (t == 0) bsums[b] = src[SCAN_B - 1];
}

__global__ __launch_bounds__(256) void scan2_kernel(const int* __restrict__ bsums,
                                                    int* __restrict__ bscan) {
  __shared__ int bufA[256], bufB[256];
  int t = threadIdx.x;
  int v = (t < SCAN_NBLK) ? bsums[t] : 0;
  bufA[t] = v;
  __syncthreads();
  int* src = bufA; int* dst = bufB;
  for (int off = 1; off < 256; off <<= 1) {
    dst[t] = src[t] + ((t >= off) ? src[t - off] : 0);
    __syncthreads();
    int* tmp = src; src = dst; dst = tmp;
  }
  if (t < SCAN_NBLK) bscan[t] = src[t] - v;
}

__global__ __launch_bounds__(256) void scan3_kernel(int* __restrict__ rowstart,
                                                    const int* __restrict__ bscan,
                                                    int* __restrict__ cursor) {
  int i = blockIdx.x * 256 + threadIdx.x;
  if (i >= N_NODES) return;
  int v = rowstart[i] + bscan[i / SCAN_B];
  rowstart[i] = v;
  cursor[i] = v;
}

// ---------------- scatter kept edges into CSR (recomputes dropout) ----------------
__global__ __launch_bounds__(256) void scatter_kernel(
    const int* __restrict__ adj32, const int* __restrict__ flag,
    const float* __restrict__ vals, int* __restrict__ cursor,
    int* __restrict__ scol, float* __restrict__ sval,
    uint32_t ke0, uint32_t ke1) {
  uint32_t e = blockIdx.x * 256u + threadIdx.x;
  if (e >= (uint32_t)N_EDGES) return;
  uint32_t eb = tf_bits(ke0, ke1, e);
  if (bits_to_unit(eb) >= PE) return;
  int fl = *flag;
  int r = fl ? adj32[2 * e] : adj32[e];
  int c = fl ? adj32[2 * (N_EDGES + e)] : adj32[N_EDGES + e];
  int pos = atomicAdd(&cursor[r], 1);
  scol[pos] = c;
  sval[pos] = vals[e] / PE;
}

// ---------------- CSR SpMM: one wave per row, write-once ----------------
__global__ __launch_bounds__(256) void spmm_csr_kernel(
    const int* __restrict__ scol, const float* __restrict__ sval,
    const int* __restrict__ rowstart, const int* __restrict__ counts,
    const float* __restrict__ h, float* __restrict__ agg) {
  int r = blockIdx.x * 4 + (threadIdx.x >> 6);
  if (r >= N_NODES) return;
  int lane = threadIdx.x & 63;
  int start = rowstart[r], len = counts[r];
  const float* hp = h + 2 * lane;
  float ax = 0.f, ay = 0.f, bx = 0.f, by = 0.f;
  int j = 0;
  for (; j + 1 < len; j += 2) {
    int c0 = scol[start + j], c1 = scol[start + j + 1];
    float v0 = sval[start + j], v1 = sval[start + j + 1];
    float2 h0 = *(const float2*)(hp + (size_t)c0 * D_H);
    float2 h1 = *(const float2*)(hp + (size_t)c1 * D_H);
    ax = fmaf(v0, h0.x, ax); ay = fmaf(v0, h0.y, ay);
    bx = fmaf(v1, h1.x, bx); by = fmaf(v1, h1.y, by);
  }
  if (j < len) {
    int c0 = scol[start + j];
    float v0 = sval[start + j];
    float2 h0 = *(const float2*)(hp + (size_t)c0 * D_H);
    ax = fmaf(v0, h0.x, ax); ay = fmaf(v0, h0.y, ay);
  }
  *(float2*)(agg + (size_t)r * D_H + 2 * lane) = make_float2(ax + bx, ay + by);
}

// ---------------- BN stats (ELU fused) ----------------
__global__ __launch_bounds__(256) void stats_kernel(const float* __restrict__ agg,
                                                    float* __restrict__ stats,
                                                    int rows_per_block) {
  __shared__ float lsum[256], lsq[256];
  int f = threadIdx.x & 127;
  int ro = threadIdx.x >> 7;
  int rstart = blockIdx.x * rows_per_block;
  int rend = min(rstart + rows_per_block, N_NODES);
  float s = 0.f, q = 0.f;
  for (int r = rstart + ro; r < rend; r += 2) {
    float a = agg[(size_t)r * D_H + f];
    float e = a > 0.f ? a : expm1f(a);
    s += e; q += e * e;
  }
  lsum[threadIdx.x] = s; lsq[threadIdx.x] = q;
  __syncthreads();
  if (threadIdx.x < 128) {
    atomicAdd(&stats[f], lsum[threadIdx.x] + lsum[threadIdx.x + 128]);
    atomicAdd(&stats[128 + f], lsq[threadIdx.x] + lsq[threadIdx.x + 128]);
  }
}

// ---------------- BN apply ----------------
__global__ __launch_bounds__(256) void bn_kernel(const float* __restrict__ agg,
                                                 const float* __restrict__ stats,
                                                 const float* __restrict__ gamma,
                                                 const float* __restrict__ beta,
                                                 float* __restrict__ out) {
  int idx4 = blockIdx.x * 256 + threadIdx.x;
  size_t base = (size_t)idx4 * 4;
  if (base >= (size_t)N_NODES * D_H) return;
  int f0 = (int)(base & 127);
  float4 a = *(const float4*)(agg + base);
  float av[4] = {a.x, a.y, a.z, a.w};
  const float inv_n = 1.0f / (float)N_NODES;
  float o[4];
  for (int j = 0; j < 4; ++j) {
    int f = f0 + j;
    float mean = stats[f] * inv_n;
    float var = stats[128 + f] * inv_n - mean * mean;
    float e = av[j] > 0.f ? av[j] : expm1f(av[j]);
    o[j] = gamma[f] * (e - mean) * rsqrtf(var + 1e-5f) + beta[f];
  }
  *(float4*)(out + base) = make_float4(o[0], o[1], o[2], o[3]);
}

// ---------------- launcher ----------------
extern "C" void kernel_launch(void* const* d_in, const int* in_sizes, int n_in,
                              void* d_out, int out_size, void* d_ws, size_t ws_size,
                              hipStream_t stream) {
  const float* data = (const float*)d_in[0];
  const int* adj = (const int*)d_in[1];
  const float* vals = (const float*)d_in[2];
  const float* W = (const float*)d_in[3];
  const float* gamma = (const float*)d_in[4];
  const float* beta = (const float*)d_in[5];
  float* out = (float*)d_out;

  // workspace layout (max offset ~154.2 MB; round-1 proved ws >= 160.1 MB):
  //   [0, 102.4M)      x (bf16)            -- dead after gemm
  //   alias zone (written only after gemm):
  //     [0, 51.2M)     agg
  //     [51.2M, 57.6M) scol
  //     [57.6M, 64.0M) sval
  //     [64.0M, 64.4M) rowstart
  //     [64.4M, 64.8M) cursor
  //     [64.8M, ...)   bsums, bscan
  //   [102.4M, 153.6M) h
  //   153,600,000      Wt (128K)
  //   153,731,072      stats (1K)
  //   153,732,096      flag (4B)
  //   153,733,120      counts (400K)       -- outside x: live during fused
  char* ws = (char*)d_ws;
  unsigned short* x = (unsigned short*)ws;
  float* agg = (float*)ws;
  int* scol = (int*)(ws + 51200000);
  float* sval = (float*)(ws + 57600000);
  int* rowstart = (int*)(ws + 64000000);
  int* cursor = (int*)(ws + 64400000);
  int* bsums = (int*)(ws + 64800000);
  int* bscan = (int*)(ws + 64801024);
  float* h = (float*)(ws + 102400000);
  unsigned short* Wt = (unsigned short*)(ws + 153600000);
  float* stats = (float*)(ws + 153731072);
  int* flag = (int*)(ws + 153732096);
  int* counts = (int*)(ws + 153733120);

  // host-side: split(key(42), 4) foldlike -> key_i = both words of tf(key,(0,i))
  uint32_t kk[4][2];
  for (uint32_t i = 0; i < 4; ++i) threefry2x32(0u, 42u, 0u, i, kk[i][0], kk[i][1]);
  uint32_t kn0 = kk[0][0], kn1 = kk[0][1];
  uint32_t kd10 = kk[1][0], kd11 = kk[1][1];
  uint32_t kd20 = kk[2][0], kd21 = kk[2][1];
  uint32_t ke0 = kk[3][0], ke1 = kk[3][1];

  detect_kernel<<<1, 64, 0, stream>>>(adj, flag);
  zero_kernel<<<391, 256, 0, stream>>>(counts, stats);
  fused_kernel<<<MAIN_BLKS + WT_BLKS, 256, 0, stream>>>(
      data, x, adj, flag, counts, W, Wt,
      kn0, kn1, kd10, kd11, kd20, kd21, ke0, ke1);
  gemm_kernel<<<(N_NODES + BM - 1) / BM, 256, 0, stream>>>(x, Wt, h);
  // ---- x dead below; alias zone live ----
  scan1_kernel<<<SCAN_NBLK, 256, 0, stream>>>(counts, rowstart, bsums);
  scan2_kernel<<<1, 256, 0, stream>>>(bsums, bscan);
  scan3_kernel<<<391, 256, 0, stream>>>(rowstart, bscan, cursor);
  scatter_kernel<<<6250, 256, 0, stream>>>(adj, flag, vals, cursor, scol, sval, ke0, ke1);
  spmm_csr_kernel<<<25000, 256, 0, stream>>>(scol, sval, rowstart, counts, h, agg);
  stats_kernel<<<400, 256, 0, stream>>>(agg, stats, 250);
  bn_kernel<<<12500, 256, 0, stream>>>(agg, stats, gamma, beta, out);
}